// Round 5
// baseline (69.137 us; speedup 1.0000x reference)
//
#include <hip/hip_runtime.h>

// Problem constants (hardcoded in the reference)
#define NPIX 65536   // 256*256 = 2^16
#define KK   361     // 19*19
#define LSZ  19
#define HWD  256
#define QB   32      // q-rows per k_part block
#define NBLK (NPIX / QB)          // 2048 k_part blocks
#define NSLOT 16     // partial slots per output row (window <= 13)
#define NS2  16      // s-strips for S1
#define SPS2 23      // s-rows per strip (last strip: 361 - 15*23 = 16)
#define DTC  50      // in2 LDS tile cols = QB-1 + LSZ

// reflect-pad index (pad=9, size 256, mode="reflect"); arg is (coord + offset)
__device__ __forceinline__ int refl(int v) {
    v -= 9;
    v = v < 0 ? -v : v;
    v = v > 255 ? 510 - v : v;
    return v;
}

// ---------------------------------------------------------------------------
// S1a: partial column sums, contiguous float4 reads.
// grid (64 p-windows, NS2 strips) x 256 thr. Each thread: one float4 acc.
// part4[strip*16384 + p4] = sum_{s in strip} ker4[s*16384 + p4]
// ---------------------------------------------------------------------------
__global__ __launch_bounds__(256) void k_s1a(const float4* __restrict__ ker4,
                                             float4* __restrict__ part4) {
    const int p4 = blockIdx.x * 256 + threadIdx.x;   // [0, 16384)
    const int strip = blockIdx.y;
    const int s0 = strip * SPS2;
    const int n = (strip == NS2 - 1) ? (KK - s0) : SPS2;
    const float4* kp = ker4 + (size_t)s0 * (NPIX / 4) + p4;
    float4 acc = {0.f, 0.f, 0.f, 0.f};
#pragma unroll 8
    for (int s = 0; s < n; ++s) {
        float4 v = kp[(size_t)s * (NPIX / 4)];
        acc.x += v.x; acc.y += v.y; acc.z += v.z; acc.w += v.w;
    }
    part4[(size_t)strip * (NPIX / 4) + p4] = acc;
}

// S1b: rcpS1[p] = 1 / sum_strips
__global__ __launch_bounds__(256) void k_s1b(const float4* __restrict__ part4,
                                             float4* __restrict__ rcp4) {
    const int i = blockIdx.x * 256 + threadIdx.x;    // [0, 16384)
    float4 a = {0.f, 0.f, 0.f, 0.f};
#pragma unroll
    for (int s = 0; s < NS2; ++s) {
        float4 v = part4[(size_t)s * (NPIX / 4) + i];
        a.x += v.x; a.y += v.y; a.z += v.z; a.w += v.w;
    }
    rcp4[i] = float4{1.0f / a.x, 1.0f / a.y, 1.0f / a.z, 1.0f / a.w};
}

// ---------------------------------------------------------------------------
// k_part: block = 32 consecutive q-rows of ker (46.2 KB contiguous -> LDS,
// scaled by rcpS1). rcpS2 per-row in-block. in2 footprint per block is a
// single 19x50 patch (y = q>>8 constant) -> staged reflected into LDS.
// Main loop: lane = t; j = t*65536 + q walks; r = j/361 piecewise-constant
// with <=1 boundary per 32-chunk -> register accumulation, <=2 partial
// stores per lane to partial[r][blockIdx & 15]. No atomics, no zeroing.
// ---------------------------------------------------------------------------
__global__ __launch_bounds__(384) void k_part(const float* __restrict__ ker,
                                              const float* __restrict__ rcpS1,
                                              const float* __restrict__ in2,
                                              float2* __restrict__ partial) {
    __shared__ float tile[QB * KK];      // 46,208 B
    __shared__ float dt[LSZ * DTC];      // 3,800 B
    __shared__ float rcpS2s[QB];
    const int tid = threadIdx.x;
    const int q0  = blockIdx.x * QB;
    const int base = q0 * KK;            // < 2^25, %4 == 0

    // stage ker slab (coalesced float4), scaled by rcpS1
    const float4* k4 = (const float4*)(ker + base);
    for (int i = tid; i < (QB * KK) / 4; i += 384) {
        float4 v = k4[i];
        int m = base + i * 4;
        const float4 s = *(const float4*)(rcpS1 + (m & (NPIX - 1)));
        v.x *= s.x; v.y *= s.y; v.z *= s.z; v.w *= s.w;
        *(float4*)(tile + i * 4) = v;
    }
    // stage reflected in2 patch: y0 constant per block (QB | 256)
    {
        const int y0 = q0 >> 8, x0 = q0 & 255;
        for (int i = tid; i < LSZ * DTC; i += 384) {
            int a = i / DTC, c = i - a * DTC;
            dt[i] = in2[refl(y0 + a) * HWD + refl(x0 + c)];
        }
    }
    __syncthreads();

    // per-q row sums -> rcpS2s
    {
        int wave = tid >> 6, lane = tid & 63;
        for (int qq = wave; qq < QB; qq += 6) {
            float a = 0.f;
            for (int e = lane; e < KK; e += 64) a += tile[qq * KK + e];
            for (int m = 1; m < 64; m <<= 1) a += __shfl_xor(a, m);
            if (lane == 0) rcpS2s[qq] = 1.0f / a;
        }
    }
    __syncthreads();

    if (tid < KK) {
        const int t  = tid;
        const int j0 = t * NPIX + q0;
        const int r0 = j0 / KK;
        const int jm = j0 - r0 * KK;
        const int d0 = (jm == 0) ? 0 : (KK - jm);
        const int split = (d0 == 0 || d0 >= QB) ? QB : d0;
        const int a = t / LSZ, b = t - LSZ * a;
        const int dbase = a * DTC + b;
        float accAd = 0.f, accAs = 0.f, accBd = 0.f, accBs = 0.f;
#pragma unroll 8
        for (int off = 0; off < QB; ++off) {
            float v = tile[off * KK + t] * rcpS2s[off];
            float d = dt[dbase + off];
            float dv = d * v;
            bool inA = off < split;
            accAd += inA ? dv : 0.f;
            accAs += inA ? v  : 0.f;
            accBd += inA ? 0.f : dv;
            accBs += inA ? 0.f : v;
        }
        const int slot = blockIdx.x & (NSLOT - 1);
        partial[(size_t)r0 * NSLOT + slot] = float2{accAd, accAs};
        if (split < QB)
            partial[(size_t)(r0 + 1) * NSLOT + slot] = float2{accBd, accBs};
    }
}

// ---------------------------------------------------------------------------
// k_out2: sum exactly the valid slot window for row r (no zero-init needed).
// Blocks touching row r: bx in [qs>>5 .. ql>>5] (mod NBLK), <= 13 wide;
// slots = bx & 15, distinct since window < 16 and 16 | NBLK.
// ---------------------------------------------------------------------------
__global__ __launch_bounds__(256) void k_out2(const float2* __restrict__ partial,
                                              float* __restrict__ out) {
    const int r = blockIdx.x * 256 + threadIdx.x;
    const int j0 = r * KK;
    const int qs = j0 & (NPIX - 1);
    const int ql = (j0 + KK - 1) & (NPIX - 1);
    const int first = qs >> 5;
    const int last  = ql >> 5;
    const int cnt = ((last - first) & (NBLK - 1)) + 1;
    const float2* p = partial + (size_t)r * NSLOT;
    float dot = 0.f, sum = 0.f;
    for (int i = 0; i < cnt; ++i) {
        float2 v = p[(first + i) & (NSLOT - 1)];
        dot += v.x; sum += v.y;
    }
    out[r] = dot / sum;
}

// ---------------------------------------------------------------------------
// Minimal fallback path (tiny ws): direct strided gathers.
// ---------------------------------------------------------------------------
__global__ __launch_bounds__(256) void k_s1(const float* __restrict__ ker,
                                            float* __restrict__ rcpS1) {
    int p = blockIdx.x * blockDim.x + threadIdx.x;
    const float* kp = ker + p;
    float a = 0.f;
    for (int s = 0; s < KK; ++s) a += kp[(size_t)s * NPIX];
    rcpS1[p] = 1.0f / a;
}

__global__ __launch_bounds__(256) void k_s2_fallback(const float* __restrict__ ker,
                                                     const float* __restrict__ rcpS1,
                                                     float* __restrict__ rcpS2) {
    int lane = threadIdx.x & 63;
    int q = blockIdx.x * 4 + (threadIdx.x >> 6);
    int base = q * KK;
    float acc = 0.f;
    for (int t = lane; t < KK; t += 64)
        acc += ker[base + t] * rcpS1[(base + t) & (NPIX - 1)];
    for (int m = 1; m < 64; m <<= 1) acc += __shfl_xor(acc, m);
    if (lane == 0) rcpS2[q] = 1.0f / acc;
}

__global__ __launch_bounds__(256) void k_out_fallback(const float* __restrict__ ker,
                                                      const float* __restrict__ rcpS1,
                                                      const float* __restrict__ rcpS2,
                                                      const float* __restrict__ in2,
                                                      float* __restrict__ out) {
    int lane = threadIdx.x & 63;
    int r = blockIdx.x * 4 + (threadIdx.x >> 6);
    float vsum = 0.f, vdot = 0.f;
    for (int u = lane; u < KK; u += 64) {
        int jj = r * KK + u;
        int t  = jj >> 16;
        int q  = jj & (NPIX - 1);
        int m  = q * KK + t;
        float v = ker[m] * rcpS1[m & (NPIX - 1)] * rcpS2[q];
        int y = q >> 8, x = q & 255;
        int a = t / LSZ, b = t - a * LSZ;
        float d = in2[refl(y + a) * HWD + refl(x + b)];
        vsum += v;
        vdot += d * v;
    }
    for (int mm = 1; mm < 64; mm <<= 1) {
        vsum += __shfl_xor(vsum, mm);
        vdot += __shfl_xor(vdot, mm);
    }
    if (lane == 0) out[r] = vdot / vsum;
}

extern "C" void kernel_launch(void* const* d_in, const int* in_sizes, int n_in,
                              void* d_out, int out_size, void* d_ws, size_t ws_size,
                              hipStream_t stream) {
    const float* inp = (const float*)d_in[0];   // (1,3,256,256)
    const float* ker = (const float*)d_in[1];   // (19,19,256,256)
    float* out = (float*)d_out;                 // (1,1,256,256)
    const float* in2 = inp + 2 * NPIX;          // channel 2

    float*  rcpS1   = (float*)d_ws;                           // NPIX
    float*  s1part  = rcpS1 + NPIX;                           // NS2*NPIX
    float2* partial = (float2*)(s1part + (size_t)NS2 * NPIX); // NPIX*NSLOT float2

    const size_t needed = ((size_t)NPIX * (1 + NS2) +
                           (size_t)NPIX * NSLOT * 2) * sizeof(float);  // ~12.25 MB

    if (ws_size >= needed) {
        dim3 g1(NPIX / 4 / 256, NS2);   // (64, 16)
        k_s1a<<<g1, 256, 0, stream>>>((const float4*)ker, (float4*)s1part);
        k_s1b<<<NPIX / 4 / 256, 256, 0, stream>>>((const float4*)s1part, (float4*)rcpS1);
        k_part<<<NBLK, 384, 0, stream>>>(ker, rcpS1, in2, partial);
        k_out2<<<NPIX / 256, 256, 0, stream>>>(partial, out);
    } else {
        float* rcpS2 = rcpS1 + NPIX;   // fallback needs only 512 KB
        k_s1<<<NPIX / 256, 256, 0, stream>>>(ker, rcpS1);
        k_s2_fallback<<<NPIX / 4, 256, 0, stream>>>(ker, rcpS1, rcpS2);
        k_out_fallback<<<NPIX / 4, 256, 0, stream>>>(ker, rcpS1, rcpS2, in2, out);
    }
}

// Round 6
// 68.966 us; speedup vs baseline: 1.0025x; 1.0025x over previous
//
#include <hip/hip_runtime.h>

// Problem constants (hardcoded in the reference)
#define NPIX 65536   // 256*256 = 2^16
#define KK   361     // 19*19
#define LSZ  19
#define HWD  256
#define QB   32      // q-rows per k_part block
#define NBLK (NPIX / QB)          // 2048 k_part blocks
#define NSLOT 16     // partial slots per output row (window <= 13)
#define NS2  16      // s-strips for S1
#define SPS2 23      // s-rows per strip (last strip: 361 - 15*23 = 16)
#define DTC  50      // in2 LDS tile cols = QB-1 + LSZ

// reflect-pad index (pad=9, size 256, mode="reflect"); arg is (coord + offset)
__device__ __forceinline__ int refl(int v) {
    v -= 9;
    v = v < 0 ? -v : v;
    v = v > 255 ? 510 - v : v;
    return v;
}

// ---------------------------------------------------------------------------
// S1a: partial column sums, contiguous float4 reads.
// grid (64 p-windows, NS2 strips) x 256 thr. Each thread: one float4 acc.
// part4[strip*16384 + p4] = sum_{s in strip} ker4[s*16384 + p4]
// ---------------------------------------------------------------------------
__global__ __launch_bounds__(256) void k_s1a(const float4* __restrict__ ker4,
                                             float4* __restrict__ part4) {
    const int p4 = blockIdx.x * 256 + threadIdx.x;   // [0, 16384)
    const int strip = blockIdx.y;
    const int s0 = strip * SPS2;
    const int n = (strip == NS2 - 1) ? (KK - s0) : SPS2;
    const float4* kp = ker4 + (size_t)s0 * (NPIX / 4) + p4;
    float4 acc = {0.f, 0.f, 0.f, 0.f};
#pragma unroll 8
    for (int s = 0; s < n; ++s) {
        float4 v = kp[(size_t)s * (NPIX / 4)];
        acc.x += v.x; acc.y += v.y; acc.z += v.z; acc.w += v.w;
    }
    part4[(size_t)strip * (NPIX / 4) + p4] = acc;
}

// S1b: rcpS1[p] = 1 / sum_strips
__global__ __launch_bounds__(256) void k_s1b(const float4* __restrict__ part4,
                                             float4* __restrict__ rcp4) {
    const int i = blockIdx.x * 256 + threadIdx.x;    // [0, 16384)
    float4 a = {0.f, 0.f, 0.f, 0.f};
#pragma unroll
    for (int s = 0; s < NS2; ++s) {
        float4 v = part4[(size_t)s * (NPIX / 4) + i];
        a.x += v.x; a.y += v.y; a.z += v.z; a.w += v.w;
    }
    rcp4[i] = float4{1.0f / a.x, 1.0f / a.y, 1.0f / a.z, 1.0f / a.w};
}

// ---------------------------------------------------------------------------
// k_part: block = 32 consecutive q-rows of ker (46.2 KB contiguous -> LDS,
// scaled by rcpS1). rcpS2 per-row in-block. in2 footprint per block is a
// single 19x50 patch (y = q>>8 constant) -> staged reflected into LDS.
// Main loop: lane = t; j = t*65536 + q walks; r = j/361 piecewise-constant
// with <=1 boundary per 32-chunk -> register accumulation, <=2 partial
// stores per lane to partial[r][blockIdx & 15]. No atomics, no zeroing.
// ---------------------------------------------------------------------------
__global__ __launch_bounds__(384) void k_part(const float* __restrict__ ker,
                                              const float* __restrict__ rcpS1,
                                              const float* __restrict__ in2,
                                              float2* __restrict__ partial) {
    __shared__ float tile[QB * KK];      // 46,208 B
    __shared__ float dt[LSZ * DTC];      // 3,800 B
    __shared__ float rcpS2s[QB];
    const int tid = threadIdx.x;
    const int q0  = blockIdx.x * QB;
    const int base = q0 * KK;            // < 2^25, %4 == 0

    // stage ker slab (coalesced float4), scaled by rcpS1
    const float4* k4 = (const float4*)(ker + base);
    for (int i = tid; i < (QB * KK) / 4; i += 384) {
        float4 v = k4[i];
        int m = base + i * 4;
        const float4 s = *(const float4*)(rcpS1 + (m & (NPIX - 1)));
        v.x *= s.x; v.y *= s.y; v.z *= s.z; v.w *= s.w;
        *(float4*)(tile + i * 4) = v;
    }
    // stage reflected in2 patch: y0 constant per block (QB | 256)
    {
        const int y0 = q0 >> 8, x0 = q0 & 255;
        for (int i = tid; i < LSZ * DTC; i += 384) {
            int a = i / DTC, c = i - a * DTC;
            dt[i] = in2[refl(y0 + a) * HWD + refl(x0 + c)];
        }
    }
    __syncthreads();

    // per-q row sums -> rcpS2s
    {
        int wave = tid >> 6, lane = tid & 63;
        for (int qq = wave; qq < QB; qq += 6) {
            float a = 0.f;
            for (int e = lane; e < KK; e += 64) a += tile[qq * KK + e];
            for (int m = 1; m < 64; m <<= 1) a += __shfl_xor(a, m);
            if (lane == 0) rcpS2s[qq] = 1.0f / a;
        }
    }
    __syncthreads();

    if (tid < KK) {
        const int t  = tid;
        const int j0 = t * NPIX + q0;
        const int r0 = j0 / KK;
        const int jm = j0 - r0 * KK;
        const int d0 = (jm == 0) ? 0 : (KK - jm);
        const int split = (d0 == 0 || d0 >= QB) ? QB : d0;
        const int a = t / LSZ, b = t - LSZ * a;
        const int dbase = a * DTC + b;
        float accAd = 0.f, accAs = 0.f, accBd = 0.f, accBs = 0.f;
#pragma unroll 8
        for (int off = 0; off < QB; ++off) {
            float v = tile[off * KK + t] * rcpS2s[off];
            float d = dt[dbase + off];
            float dv = d * v;
            bool inA = off < split;
            accAd += inA ? dv : 0.f;
            accAs += inA ? v  : 0.f;
            accBd += inA ? 0.f : dv;
            accBs += inA ? 0.f : v;
        }
        const int slot = blockIdx.x & (NSLOT - 1);
        partial[(size_t)r0 * NSLOT + slot] = float2{accAd, accAs};
        if (split < QB)
            partial[(size_t)(r0 + 1) * NSLOT + slot] = float2{accBd, accBs};
    }
}

// ---------------------------------------------------------------------------
// k_out2: sum exactly the valid slot window for row r (no zero-init needed).
// Blocks touching row r: bx in [qs>>5 .. ql>>5] (mod NBLK), <= 13 wide;
// slots = bx & 15, distinct since window < 16 and 16 | NBLK.
// ---------------------------------------------------------------------------
__global__ __launch_bounds__(256) void k_out2(const float2* __restrict__ partial,
                                              float* __restrict__ out) {
    const int r = blockIdx.x * 256 + threadIdx.x;
    const int j0 = r * KK;
    const int qs = j0 & (NPIX - 1);
    const int ql = (j0 + KK - 1) & (NPIX - 1);
    const int first = qs >> 5;
    const int last  = ql >> 5;
    const int cnt = ((last - first) & (NBLK - 1)) + 1;
    const float2* p = partial + (size_t)r * NSLOT;
    float dot = 0.f, sum = 0.f;
    for (int i = 0; i < cnt; ++i) {
        float2 v = p[(first + i) & (NSLOT - 1)];
        dot += v.x; sum += v.y;
    }
    out[r] = dot / sum;
}

// ---------------------------------------------------------------------------
// Minimal fallback path (tiny ws): direct strided gathers.
// ---------------------------------------------------------------------------
__global__ __launch_bounds__(256) void k_s1(const float* __restrict__ ker,
                                            float* __restrict__ rcpS1) {
    int p = blockIdx.x * blockDim.x + threadIdx.x;
    const float* kp = ker + p;
    float a = 0.f;
    for (int s = 0; s < KK; ++s) a += kp[(size_t)s * NPIX];
    rcpS1[p] = 1.0f / a;
}

__global__ __launch_bounds__(256) void k_s2_fallback(const float* __restrict__ ker,
                                                     const float* __restrict__ rcpS1,
                                                     float* __restrict__ rcpS2) {
    int lane = threadIdx.x & 63;
    int q = blockIdx.x * 4 + (threadIdx.x >> 6);
    int base = q * KK;
    float acc = 0.f;
    for (int t = lane; t < KK; t += 64)
        acc += ker[base + t] * rcpS1[(base + t) & (NPIX - 1)];
    for (int m = 1; m < 64; m <<= 1) acc += __shfl_xor(acc, m);
    if (lane == 0) rcpS2[q] = 1.0f / acc;
}

__global__ __launch_bounds__(256) void k_out_fallback(const float* __restrict__ ker,
                                                      const float* __restrict__ rcpS1,
                                                      const float* __restrict__ rcpS2,
                                                      const float* __restrict__ in2,
                                                      float* __restrict__ out) {
    int lane = threadIdx.x & 63;
    int r = blockIdx.x * 4 + (threadIdx.x >> 6);
    float vsum = 0.f, vdot = 0.f;
    for (int u = lane; u < KK; u += 64) {
        int jj = r * KK + u;
        int t  = jj >> 16;
        int q  = jj & (NPIX - 1);
        int m  = q * KK + t;
        float v = ker[m] * rcpS1[m & (NPIX - 1)] * rcpS2[q];
        int y = q >> 8, x = q & 255;
        int a = t / LSZ, b = t - a * LSZ;
        float d = in2[refl(y + a) * HWD + refl(x + b)];
        vsum += v;
        vdot += d * v;
    }
    for (int mm = 1; mm < 64; mm <<= 1) {
        vsum += __shfl_xor(vsum, mm);
        vdot += __shfl_xor(vdot, mm);
    }
    if (lane == 0) out[r] = vdot / vsum;
}

extern "C" void kernel_launch(void* const* d_in, const int* in_sizes, int n_in,
                              void* d_out, int out_size, void* d_ws, size_t ws_size,
                              hipStream_t stream) {
    const float* inp = (const float*)d_in[0];   // (1,3,256,256)
    const float* ker = (const float*)d_in[1];   // (19,19,256,256)
    float* out = (float*)d_out;                 // (1,1,256,256)
    const float* in2 = inp + 2 * NPIX;          // channel 2

    float*  rcpS1   = (float*)d_ws;                           // NPIX
    float*  s1part  = rcpS1 + NPIX;                           // NS2*NPIX
    float2* partial = (float2*)(s1part + (size_t)NS2 * NPIX); // NPIX*NSLOT float2

    const size_t needed = ((size_t)NPIX * (1 + NS2) +
                           (size_t)NPIX * NSLOT * 2) * sizeof(float);  // ~12.25 MB

    if (ws_size >= needed) {
        dim3 g1(NPIX / 4 / 256, NS2);   // (64, 16)
        k_s1a<<<g1, 256, 0, stream>>>((const float4*)ker, (float4*)s1part);
        k_s1b<<<NPIX / 4 / 256, 256, 0, stream>>>((const float4*)s1part, (float4*)rcpS1);
        k_part<<<NBLK, 384, 0, stream>>>(ker, rcpS1, in2, partial);
        k_out2<<<NPIX / 256, 256, 0, stream>>>(partial, out);
    } else {
        float* rcpS2 = rcpS1 + NPIX;   // fallback needs only 512 KB
        k_s1<<<NPIX / 256, 256, 0, stream>>>(ker, rcpS1);
        k_s2_fallback<<<NPIX / 4, 256, 0, stream>>>(ker, rcpS1, rcpS2);
        k_out_fallback<<<NPIX / 4, 256, 0, stream>>>(ker, rcpS1, rcpS2, in2, out);
    }
}

// Round 7
// 64.458 us; speedup vs baseline: 1.0726x; 1.0699x over previous
//
#include <hip/hip_runtime.h>

// Problem constants (hardcoded in the reference)
#define NPIX 65536   // 256*256 = 2^16
#define KK   361     // 19*19
#define LSZ  19
#define HWD  256
#define QB   32      // q-rows per k_part block
#define NBLK (NPIX / QB)          // 2048 k_part blocks
#define NSLOT 16     // partial slots per output row (window <= 13)
#define NS2  16      // s-strips for S1
#define SPS2 23      // s-rows per strip (last strip: 361 - 15*23 = 16)
#define DTC  50      // in2 LDS tile cols = QB-1 + LSZ

// reflect-pad index (pad=9, size 256, mode="reflect"); arg is (coord + offset)
__device__ __forceinline__ int refl(int v) {
    v -= 9;
    v = v < 0 ? -v : v;
    v = v > 255 ? 510 - v : v;
    return v;
}

// ---------------------------------------------------------------------------
// S1a: partial column sums, contiguous float4 reads.
// grid (64 p-windows, NS2 strips) x 256 thr. Each thread: one float4 acc.
// ---------------------------------------------------------------------------
__global__ __launch_bounds__(256) void k_s1a(const float4* __restrict__ ker4,
                                             float4* __restrict__ part4) {
    const int p4 = blockIdx.x * 256 + threadIdx.x;   // [0, 16384)
    const int strip = blockIdx.y;
    const int s0 = strip * SPS2;
    const int n = (strip == NS2 - 1) ? (KK - s0) : SPS2;
    const float4* kp = ker4 + (size_t)s0 * (NPIX / 4) + p4;
    float4 acc = {0.f, 0.f, 0.f, 0.f};
#pragma unroll 8
    for (int s = 0; s < n; ++s) {
        float4 v = kp[(size_t)s * (NPIX / 4)];
        acc.x += v.x; acc.y += v.y; acc.z += v.z; acc.w += v.w;
    }
    part4[(size_t)strip * (NPIX / 4) + p4] = acc;
}

// S1b: rcpS1[p] = 1 / sum_strips
__global__ __launch_bounds__(256) void k_s1b(const float4* __restrict__ part4,
                                             float4* __restrict__ rcp4) {
    const int i = blockIdx.x * 256 + threadIdx.x;    // [0, 16384)
    float4 a = {0.f, 0.f, 0.f, 0.f};
#pragma unroll
    for (int s = 0; s < NS2; ++s) {
        float4 v = part4[(size_t)s * (NPIX / 4) + i];
        a.x += v.x; a.y += v.y; a.z += v.z; a.w += v.w;
    }
    rcp4[i] = float4{1.0f / a.x, 1.0f / a.y, 1.0f / a.z, 1.0f / a.w};
}

// ---------------------------------------------------------------------------
// k_part: block = 32 consecutive q-rows of ker (46.2 KB contiguous -> LDS,
// scaled by rcpS1). rcpS2 per-row in-block. in2 footprint per block is a
// single 19x50 patch (y = q>>8 constant) -> staged reflected into LDS.
// Main loop: lane = t; j = t*65536 + q walks; r = j/361 piecewise-constant
// with <=1 boundary per 32-chunk -> register accumulation, <=2 partial
// stores per lane to partial[r][lb & 15]. No atomics, no zeroing.
//
// XCD swizzle: the <=13 blocks writing the same partial row-region are
// CONSECUTIVE logical blocks; map them to the same XCD so their 8B stores
// into shared 64B lines combine in one (non-cross-coherent) L2 instead of
// false-sharing across all 8 XCDs. lb = (bid&7)*256 + bid>>3 (bijective,
// 2048 = 8*256); dispatch round-robin => each logical group of 256 stays
// on one XCD.
// ---------------------------------------------------------------------------
__global__ __launch_bounds__(384) void k_part(const float* __restrict__ ker,
                                              const float* __restrict__ rcpS1,
                                              const float* __restrict__ in2,
                                              float2* __restrict__ partial) {
    __shared__ float tile[QB * KK];      // 46,208 B
    __shared__ float dt[LSZ * DTC];      // 3,800 B
    __shared__ float rcpS2s[QB];
    const int tid = threadIdx.x;
    const int lb  = ((blockIdx.x & 7) << 8) | (blockIdx.x >> 3);  // logical block
    const int q0  = lb * QB;
    const int base = q0 * KK;            // < 2^25, %4 == 0

    // stage ker slab (coalesced float4), scaled by rcpS1
    const float4* k4 = (const float4*)(ker + base);
    for (int i = tid; i < (QB * KK) / 4; i += 384) {
        float4 v = k4[i];
        int m = base + i * 4;
        const float4 s = *(const float4*)(rcpS1 + (m & (NPIX - 1)));
        v.x *= s.x; v.y *= s.y; v.z *= s.z; v.w *= s.w;
        *(float4*)(tile + i * 4) = v;
    }
    // stage reflected in2 patch: y0 constant per block (QB | 256)
    {
        const int y0 = q0 >> 8, x0 = q0 & 255;
        for (int i = tid; i < LSZ * DTC; i += 384) {
            int a = i / DTC, c = i - a * DTC;
            dt[i] = in2[refl(y0 + a) * HWD + refl(x0 + c)];
        }
    }
    __syncthreads();

    // per-q row sums -> rcpS2s
    {
        int wave = tid >> 6, lane = tid & 63;
        for (int qq = wave; qq < QB; qq += 6) {
            float a = 0.f;
            for (int e = lane; e < KK; e += 64) a += tile[qq * KK + e];
            for (int m = 1; m < 64; m <<= 1) a += __shfl_xor(a, m);
            if (lane == 0) rcpS2s[qq] = 1.0f / a;
        }
    }
    __syncthreads();

    if (tid < KK) {
        const int t  = tid;
        const int j0 = t * NPIX + q0;
        const int r0 = j0 / KK;
        const int jm = j0 - r0 * KK;
        const int d0 = (jm == 0) ? 0 : (KK - jm);
        const int split = (d0 == 0 || d0 >= QB) ? QB : d0;
        const int a = t / LSZ, b = t - LSZ * a;
        const int dbase = a * DTC + b;
        float accAd = 0.f, accAs = 0.f, accBd = 0.f, accBs = 0.f;
#pragma unroll 8
        for (int off = 0; off < QB; ++off) {
            float v = tile[off * KK + t] * rcpS2s[off];
            float d = dt[dbase + off];
            float dv = d * v;
            bool inA = off < split;
            accAd += inA ? dv : 0.f;
            accAs += inA ? v  : 0.f;
            accBd += inA ? 0.f : dv;
            accBs += inA ? 0.f : v;
        }
        const int slot = lb & (NSLOT - 1);
        partial[(size_t)r0 * NSLOT + slot] = float2{accAd, accAs};
        if (split < QB)
            partial[(size_t)(r0 + 1) * NSLOT + slot] = float2{accBd, accBs};
    }
}

// ---------------------------------------------------------------------------
// k_out2: sum exactly the valid slot window for row r (no zero-init needed).
// Blocks touching row r: lb in [qs>>5 .. ql>>5] (mod NBLK), <= 13 wide;
// slots = lb & 15, distinct since window < 16 and 16 | NBLK.
// ---------------------------------------------------------------------------
__global__ __launch_bounds__(256) void k_out2(const float2* __restrict__ partial,
                                              float* __restrict__ out) {
    const int r = blockIdx.x * 256 + threadIdx.x;
    const int j0 = r * KK;
    const int qs = j0 & (NPIX - 1);
    const int ql = (j0 + KK - 1) & (NPIX - 1);
    const int first = qs >> 5;
    const int last  = ql >> 5;
    const int cnt = ((last - first) & (NBLK - 1)) + 1;
    const float2* p = partial + (size_t)r * NSLOT;
    float dot = 0.f, sum = 0.f;
    for (int i = 0; i < cnt; ++i) {
        float2 v = p[(first + i) & (NSLOT - 1)];
        dot += v.x; sum += v.y;
    }
    out[r] = dot / sum;
}

// ---------------------------------------------------------------------------
// Minimal fallback path (tiny ws): direct strided gathers.
// ---------------------------------------------------------------------------
__global__ __launch_bounds__(256) void k_s1(const float* __restrict__ ker,
                                            float* __restrict__ rcpS1) {
    int p = blockIdx.x * blockDim.x + threadIdx.x;
    const float* kp = ker + p;
    float a = 0.f;
    for (int s = 0; s < KK; ++s) a += kp[(size_t)s * NPIX];
    rcpS1[p] = 1.0f / a;
}

__global__ __launch_bounds__(256) void k_s2_fallback(const float* __restrict__ ker,
                                                     const float* __restrict__ rcpS1,
                                                     float* __restrict__ rcpS2) {
    int lane = threadIdx.x & 63;
    int q = blockIdx.x * 4 + (threadIdx.x >> 6);
    int base = q * KK;
    float acc = 0.f;
    for (int t = lane; t < KK; t += 64)
        acc += ker[base + t] * rcpS1[(base + t) & (NPIX - 1)];
    for (int m = 1; m < 64; m <<= 1) acc += __shfl_xor(acc, m);
    if (lane == 0) rcpS2[q] = 1.0f / acc;
}

__global__ __launch_bounds__(256) void k_out_fallback(const float* __restrict__ ker,
                                                      const float* __restrict__ rcpS1,
                                                      const float* __restrict__ rcpS2,
                                                      const float* __restrict__ in2,
                                                      float* __restrict__ out) {
    int lane = threadIdx.x & 63;
    int r = blockIdx.x * 4 + (threadIdx.x >> 6);
    float vsum = 0.f, vdot = 0.f;
    for (int u = lane; u < KK; u += 64) {
        int jj = r * KK + u;
        int t  = jj >> 16;
        int q  = jj & (NPIX - 1);
        int m  = q * KK + t;
        float v = ker[m] * rcpS1[m & (NPIX - 1)] * rcpS2[q];
        int y = q >> 8, x = q & 255;
        int a = t / LSZ, b = t - a * LSZ;
        float d = in2[refl(y + a) * HWD + refl(x + b)];
        vsum += v;
        vdot += d * v;
    }
    for (int mm = 1; mm < 64; mm <<= 1) {
        vsum += __shfl_xor(vsum, mm);
        vdot += __shfl_xor(vdot, mm);
    }
    if (lane == 0) out[r] = vdot / vsum;
}

extern "C" void kernel_launch(void* const* d_in, const int* in_sizes, int n_in,
                              void* d_out, int out_size, void* d_ws, size_t ws_size,
                              hipStream_t stream) {
    const float* inp = (const float*)d_in[0];   // (1,3,256,256)
    const float* ker = (const float*)d_in[1];   // (19,19,256,256)
    float* out = (float*)d_out;                 // (1,1,256,256)
    const float* in2 = inp + 2 * NPIX;          // channel 2

    float*  rcpS1   = (float*)d_ws;                           // NPIX
    float*  s1part  = rcpS1 + NPIX;                           // NS2*NPIX
    float2* partial = (float2*)(s1part + (size_t)NS2 * NPIX); // NPIX*NSLOT float2

    const size_t needed = ((size_t)NPIX * (1 + NS2) +
                           (size_t)NPIX * NSLOT * 2) * sizeof(float);  // ~12.25 MB

    if (ws_size >= needed) {
        dim3 g1(NPIX / 4 / 256, NS2);   // (64, 16)
        k_s1a<<<g1, 256, 0, stream>>>((const float4*)ker, (float4*)s1part);
        k_s1b<<<NPIX / 4 / 256, 256, 0, stream>>>((const float4*)s1part, (float4*)rcpS1);
        k_part<<<NBLK, 384, 0, stream>>>(ker, rcpS1, in2, partial);
        k_out2<<<NPIX / 256, 256, 0, stream>>>(partial, out);
    } else {
        float* rcpS2 = rcpS1 + NPIX;   // fallback needs only 512 KB
        k_s1<<<NPIX / 256, 256, 0, stream>>>(ker, rcpS1);
        k_s2_fallback<<<NPIX / 4, 256, 0, stream>>>(ker, rcpS1, rcpS2);
        k_out_fallback<<<NPIX / 4, 256, 0, stream>>>(ker, rcpS1, rcpS2, in2, out);
    }
}

// Round 8
// 61.516 us; speedup vs baseline: 1.1239x; 1.0478x over previous
//
#include <hip/hip_runtime.h>

// Problem constants (hardcoded in the reference)
#define NPIX 65536   // 256*256 = 2^16
#define KK   361     // 19*19
#define LSZ  19
#define HWD  256
#define QB   16      // q-rows per k_part block
#define NBLK (NPIX / QB)          // 4096 k_part blocks
#define NSLOT 32     // partial slots per output row (window <= 24)
#define NS2  16      // s-strips for S1
#define SPS2 23      // s-rows per strip (last strip: 361 - 15*23 = 16)
#define DTC  34      // in2 LDS tile cols = QB-1 + LSZ

// reflect-pad index (pad=9, size 256, mode="reflect"); arg is (coord + offset)
__device__ __forceinline__ int refl(int v) {
    v -= 9;
    v = v < 0 ? -v : v;
    v = v > 255 ? 510 - v : v;
    return v;
}

// ---------------------------------------------------------------------------
// S1a: partial column sums, contiguous float4 reads.
// ---------------------------------------------------------------------------
__global__ __launch_bounds__(256) void k_s1a(const float4* __restrict__ ker4,
                                             float4* __restrict__ part4) {
    const int p4 = blockIdx.x * 256 + threadIdx.x;   // [0, 16384)
    const int strip = blockIdx.y;
    const int s0 = strip * SPS2;
    const int n = (strip == NS2 - 1) ? (KK - s0) : SPS2;
    const float4* kp = ker4 + (size_t)s0 * (NPIX / 4) + p4;
    float4 acc = {0.f, 0.f, 0.f, 0.f};
#pragma unroll 8
    for (int s = 0; s < n; ++s) {
        float4 v = kp[(size_t)s * (NPIX / 4)];
        acc.x += v.x; acc.y += v.y; acc.z += v.z; acc.w += v.w;
    }
    part4[(size_t)strip * (NPIX / 4) + p4] = acc;
}

// S1b: rcpS1[p] = 1 / sum_strips
__global__ __launch_bounds__(256) void k_s1b(const float4* __restrict__ part4,
                                             float4* __restrict__ rcp4) {
    const int i = blockIdx.x * 256 + threadIdx.x;    // [0, 16384)
    float4 a = {0.f, 0.f, 0.f, 0.f};
#pragma unroll
    for (int s = 0; s < NS2; ++s) {
        float4 v = part4[(size_t)s * (NPIX / 4) + i];
        a.x += v.x; a.y += v.y; a.z += v.z; a.w += v.w;
    }
    rcp4[i] = float4{1.0f / a.x, 1.0f / a.y, 1.0f / a.z, 1.0f / a.w};
}

// ---------------------------------------------------------------------------
// k_part: block = QB=16 consecutive q-rows of ker (23.1 KB -> LDS, scaled by
// rcpS1). ~26 KB LDS/block -> 5 blocks/CU = 30 waves/CU (was 18 at QB=32).
// Main loop fully unrolled; single accumulator + snapshot at the row
// boundary (B = total - snapshot), replacing 8 predicated ops/iter with 2.
// XCD swizzle: consecutive logical blocks (co-writers of a partial row
// region) map to the same XCD: lb = (bid&7)*512 + bid>>3.
// ---------------------------------------------------------------------------
__global__ __launch_bounds__(384) void k_part(const float* __restrict__ ker,
                                              const float* __restrict__ rcpS1,
                                              const float* __restrict__ in2,
                                              float2* __restrict__ partial) {
    __shared__ float tile[QB * KK];      // 23,104 B
    __shared__ float dt[LSZ * DTC];      // 2,584 B
    __shared__ float rcpS2s[QB];
    const int tid = threadIdx.x;
    const int lb  = ((blockIdx.x & 7) << 9) | (blockIdx.x >> 3);  // logical block
    const int q0  = lb * QB;
    const int base = q0 * KK;            // < 2^25, %4 == 0

    // stage ker slab (coalesced float4), scaled by rcpS1
    const float4* k4 = (const float4*)(ker + base);
    for (int i = tid; i < (QB * KK) / 4; i += 384) {
        float4 v = k4[i];
        int m = base + i * 4;
        const float4 s = *(const float4*)(rcpS1 + (m & (NPIX - 1)));
        v.x *= s.x; v.y *= s.y; v.z *= s.z; v.w *= s.w;
        *(float4*)(tile + i * 4) = v;
    }
    // stage reflected in2 patch: y0 constant per block (QB | 256)
    {
        const int y0 = q0 >> 8, x0 = q0 & 255;
        for (int i = tid; i < LSZ * DTC; i += 384) {
            int a = i / DTC, c = i - a * DTC;
            dt[i] = in2[refl(y0 + a) * HWD + refl(x0 + c)];
        }
    }
    __syncthreads();

    // per-q row sums -> rcpS2s
    {
        int wave = tid >> 6, lane = tid & 63;
        for (int qq = wave; qq < QB; qq += 6) {
            float a = 0.f;
            for (int e = lane; e < KK; e += 64) a += tile[qq * KK + e];
            for (int m = 1; m < 64; m <<= 1) a += __shfl_xor(a, m);
            if (lane == 0) rcpS2s[qq] = 1.0f / a;
        }
    }
    __syncthreads();

    if (tid < KK) {
        const int t  = tid;
        const int j0 = t * NPIX + q0;
        const int r0 = j0 / KK;
        const int jm = j0 - r0 * KK;
        const int d0 = (jm == 0) ? QB : (KK - jm);   // elems left in row r0
        const int split = d0 < QB ? d0 : QB;         // [1, QB]
        const int a = t / LSZ, b = t - LSZ * a;
        const int dbase = a * DTC + b;
        float ad = 0.f, as = 0.f, sd = 0.f, ss = 0.f;
#pragma unroll
        for (int off = 0; off < QB; ++off) {
            if (off == split) { sd = ad; ss = as; }  // snapshot at row boundary
            float v = tile[off * KK + t] * rcpS2s[off];
            float d = dt[dbase + off];
            ad += d * v;
            as += v;
        }
        const int slot = lb & (NSLOT - 1);
        if (split == QB) {
            partial[(size_t)r0 * NSLOT + slot] = float2{ad, as};
        } else {
            partial[(size_t)r0 * NSLOT + slot] = float2{sd, ss};
            partial[(size_t)(r0 + 1) * NSLOT + slot] = float2{ad - sd, as - ss};
        }
    }
}

// ---------------------------------------------------------------------------
// k_out2: sum exactly the valid slot window for row r (no zero-init needed).
// Blocks touching row r: lb in [qs>>4 .. ql>>4] (mod NBLK), <= 24 wide;
// slots = lb & 31, distinct since window < 32 and 32 | NBLK.
// ---------------------------------------------------------------------------
__global__ __launch_bounds__(256) void k_out2(const float2* __restrict__ partial,
                                              float* __restrict__ out) {
    const int r = blockIdx.x * 256 + threadIdx.x;
    const int j0 = r * KK;
    const int qs = j0 & (NPIX - 1);
    const int ql = (j0 + KK - 1) & (NPIX - 1);
    const int first = qs >> 4;
    const int last  = ql >> 4;
    const int cnt = ((last - first) & (NBLK - 1)) + 1;
    const float2* p = partial + (size_t)r * NSLOT;
    float dot = 0.f, sum = 0.f;
    for (int i = 0; i < cnt; ++i) {
        float2 v = p[(first + i) & (NSLOT - 1)];
        dot += v.x; sum += v.y;
    }
    out[r] = dot / sum;
}

// ---------------------------------------------------------------------------
// Minimal fallback path (tiny ws): direct strided gathers.
// ---------------------------------------------------------------------------
__global__ __launch_bounds__(256) void k_s1(const float* __restrict__ ker,
                                            float* __restrict__ rcpS1) {
    int p = blockIdx.x * blockDim.x + threadIdx.x;
    const float* kp = ker + p;
    float a = 0.f;
    for (int s = 0; s < KK; ++s) a += kp[(size_t)s * NPIX];
    rcpS1[p] = 1.0f / a;
}

__global__ __launch_bounds__(256) void k_s2_fallback(const float* __restrict__ ker,
                                                     const float* __restrict__ rcpS1,
                                                     float* __restrict__ rcpS2) {
    int lane = threadIdx.x & 63;
    int q = blockIdx.x * 4 + (threadIdx.x >> 6);
    int base = q * KK;
    float acc = 0.f;
    for (int t = lane; t < KK; t += 64)
        acc += ker[base + t] * rcpS1[(base + t) & (NPIX - 1)];
    for (int m = 1; m < 64; m <<= 1) acc += __shfl_xor(acc, m);
    if (lane == 0) rcpS2[q] = 1.0f / acc;
}

__global__ __launch_bounds__(256) void k_out_fallback(const float* __restrict__ ker,
                                                      const float* __restrict__ rcpS1,
                                                      const float* __restrict__ rcpS2,
                                                      const float* __restrict__ in2,
                                                      float* __restrict__ out) {
    int lane = threadIdx.x & 63;
    int r = blockIdx.x * 4 + (threadIdx.x >> 6);
    float vsum = 0.f, vdot = 0.f;
    for (int u = lane; u < KK; u += 64) {
        int jj = r * KK + u;
        int t  = jj >> 16;
        int q  = jj & (NPIX - 1);
        int m  = q * KK + t;
        float v = ker[m] * rcpS1[m & (NPIX - 1)] * rcpS2[q];
        int y = q >> 8, x = q & 255;
        int a = t / LSZ, b = t - a * LSZ;
        float d = in2[refl(y + a) * HWD + refl(x + b)];
        vsum += v;
        vdot += d * v;
    }
    for (int mm = 1; mm < 64; mm <<= 1) {
        vsum += __shfl_xor(vsum, mm);
        vdot += __shfl_xor(vdot, mm);
    }
    if (lane == 0) out[r] = vdot / vsum;
}

extern "C" void kernel_launch(void* const* d_in, const int* in_sizes, int n_in,
                              void* d_out, int out_size, void* d_ws, size_t ws_size,
                              hipStream_t stream) {
    const float* inp = (const float*)d_in[0];   // (1,3,256,256)
    const float* ker = (const float*)d_in[1];   // (19,19,256,256)
    float* out = (float*)d_out;                 // (1,1,256,256)
    const float* in2 = inp + 2 * NPIX;          // channel 2

    float*  rcpS1   = (float*)d_ws;                           // NPIX
    float*  s1part  = rcpS1 + NPIX;                           // NS2*NPIX
    float2* partial = (float2*)(s1part + (size_t)NS2 * NPIX); // NPIX*NSLOT float2

    const size_t needed = ((size_t)NPIX * (1 + NS2) +
                           (size_t)NPIX * NSLOT * 2) * sizeof(float);  // ~21.2 MB

    if (ws_size >= needed) {
        dim3 g1(NPIX / 4 / 256, NS2);   // (64, 16)
        k_s1a<<<g1, 256, 0, stream>>>((const float4*)ker, (float4*)s1part);
        k_s1b<<<NPIX / 4 / 256, 256, 0, stream>>>((const float4*)s1part, (float4*)rcpS1);
        k_part<<<NBLK, 384, 0, stream>>>(ker, rcpS1, in2, partial);
        k_out2<<<NPIX / 256, 256, 0, stream>>>(partial, out);
    } else {
        float* rcpS2 = rcpS1 + NPIX;   // fallback needs only 512 KB
        k_s1<<<NPIX / 256, 256, 0, stream>>>(ker, rcpS1);
        k_s2_fallback<<<NPIX / 4, 256, 0, stream>>>(ker, rcpS1, rcpS2);
        k_out_fallback<<<NPIX / 4, 256, 0, stream>>>(ker, rcpS1, rcpS2, in2, out);
    }
}

// Round 9
// 51.415 us; speedup vs baseline: 1.3447x; 1.1965x over previous
//
#include <hip/hip_runtime.h>

// Problem constants (hardcoded in the reference)
#define NPIX 65536   // 256*256 = 2^16
#define KK   361     // 19*19
#define LSZ  19
#define HWD  256
#define QB   16      // q-rows per tile
#define CT   4       // tiles per block chunk (64 q per chunk)
#define GPART 1024   // k_part grid = NPIX/(QB*CT)
#define NSLOT 8      // partial slots per row (window <= 7, one 64B line)
#define NS2  16      // s-strips for S1
#define SPS2 23      // s-rows per strip (last strip: 361 - 15*23 = 16)
#define DTC  82      // in2 LDS tile cols = QB*CT-1 + LSZ

// reflect-pad index (pad=9, size 256, mode="reflect"); arg is (coord + offset)
__device__ __forceinline__ int refl(int v) {
    v -= 9;
    v = v < 0 ? -v : v;
    v = v > 255 ? 510 - v : v;
    return v;
}

// ---------------------------------------------------------------------------
// S1a: partial column sums, contiguous float4 reads.
// ---------------------------------------------------------------------------
__global__ __launch_bounds__(256) void k_s1a(const float4* __restrict__ ker4,
                                             float4* __restrict__ part4) {
    const int p4 = blockIdx.x * 256 + threadIdx.x;   // [0, 16384)
    const int strip = blockIdx.y;
    const int s0 = strip * SPS2;
    const int n = (strip == NS2 - 1) ? (KK - s0) : SPS2;
    const float4* kp = ker4 + (size_t)s0 * (NPIX / 4) + p4;
    float4 acc = {0.f, 0.f, 0.f, 0.f};
#pragma unroll 8
    for (int s = 0; s < n; ++s) {
        float4 v = kp[(size_t)s * (NPIX / 4)];
        acc.x += v.x; acc.y += v.y; acc.z += v.z; acc.w += v.w;
    }
    part4[(size_t)strip * (NPIX / 4) + p4] = acc;
}

// S1b: rcpS1[p] = 1 / sum_strips
__global__ __launch_bounds__(256) void k_s1b(const float4* __restrict__ part4,
                                             float4* __restrict__ rcp4) {
    const int i = blockIdx.x * 256 + threadIdx.x;    // [0, 16384)
    float4 a = {0.f, 0.f, 0.f, 0.f};
#pragma unroll
    for (int s = 0; s < NS2; ++s) {
        float4 v = part4[(size_t)s * (NPIX / 4) + i];
        a.x += v.x; a.y += v.y; a.z += v.z; a.w += v.w;
    }
    rcp4[i] = float4{1.0f / a.x, 1.0f / a.y, 1.0f / a.z, 1.0f / a.w};
}

// ---------------------------------------------------------------------------
// k_part (chunked-carry): block = CT=4 consecutive 16-row tiles (64 q).
// Each lane t carries its (dot,sum) register accumulator ACROSS tiles; a
// 64-q chunk crosses at most one row boundary (64 < 361), handled by the
// snapshot trick once per chunk. Partial stores: <=2 per lane per chunk
// (3.7x fewer than per-tile). dt patch staged once per chunk (y0 constant,
// x never crosses 256 inside a chunk). Per tile: stage ker slab -> LDS
// (scaled by rcpS1), row-sums -> rcpS2s, then 16 accumulate steps.
// ---------------------------------------------------------------------------
__global__ __launch_bounds__(384) void k_part(const float* __restrict__ ker,
                                              const float* __restrict__ rcpS1,
                                              const float* __restrict__ in2,
                                              float2* __restrict__ partial) {
    __shared__ float tile[QB * KK];      // 23,104 B
    __shared__ float dt[LSZ * DTC];      // 6,232 B
    __shared__ float rcpS2s[QB];
    const int tid = threadIdx.x;
    const int q0  = blockIdx.x * (QB * CT);

    // stage reflected in2 patch once per chunk: y0 constant, width 82
    {
        const int y0 = q0 >> 8, x0 = q0 & 255;
        for (int i = tid; i < LSZ * DTC; i += 384) {
            int a = i / DTC, c = i - a * DTC;
            dt[i] = in2[refl(y0 + a) * HWD + refl(x0 + c)];
        }
    }

    // per-lane chunk-carry state
    const int t  = tid;                       // lane id == kernel-pos t
    const int j0 = t * NPIX + q0;             // < 2^25
    const int r0 = j0 / KK;
    const int jm = j0 - r0 * KK;
    const int d0 = (jm == 0) ? (QB * CT) : (KK - jm);
    const int split = d0 < (QB * CT) ? d0 : (QB * CT);   // [1, 64]
    const int a = t / LSZ, b = t - LSZ * a;
    const int dbase = a * DTC + b;
    float ad = 0.f, as = 0.f, sd = 0.f, ss = 0.f;

    for (int k = 0; k < CT; ++k) {
        __syncthreads();   // previous tile fully consumed (and dt staged, k=0)
        // stage ker tile k (coalesced float4), scaled by rcpS1
        const int basek = (q0 + k * QB) * KK;            // %4 == 0
        const float4* k4 = (const float4*)(ker + basek);
        for (int i = tid; i < (QB * KK) / 4; i += 384) {
            float4 v = k4[i];
            int m = basek + i * 4;
            const float4 s = *(const float4*)(rcpS1 + (m & (NPIX - 1)));
            v.x *= s.x; v.y *= s.y; v.z *= s.z; v.w *= s.w;
            *(float4*)(tile + i * 4) = v;
        }
        __syncthreads();
        // per-q row sums -> rcpS2s
        {
            int wave = tid >> 6, lane = tid & 63;
            for (int qq = wave; qq < QB; qq += 6) {
                float acc = 0.f;
                for (int e = lane; e < KK; e += 64) acc += tile[qq * KK + e];
                for (int m = 1; m < 64; m <<= 1) acc += __shfl_xor(acc, m);
                if (lane == 0) rcpS2s[qq] = 1.0f / acc;
            }
        }
        __syncthreads();
        if (t < KK) {
#pragma unroll
            for (int o = 0; o < QB; ++o) {
                int off = k * QB + o;
                if (off == split) { sd = ad; ss = as; }  // snapshot at boundary
                float v = tile[o * KK + t] * rcpS2s[o];
                float d = dt[dbase + off];
                ad += d * v;
                as += v;
            }
        }
    }

    if (t < KK) {
        const int slot = blockIdx.x & (NSLOT - 1);
        if (split == QB * CT) {
            partial[(size_t)r0 * NSLOT + slot] = float2{ad, as};
        } else {
            partial[(size_t)r0 * NSLOT + slot] = float2{sd, ss};
            partial[(size_t)(r0 + 1) * NSLOT + slot] = float2{ad - sd, as - ss};
        }
    }
}

// ---------------------------------------------------------------------------
// k_out2: sum the valid slot window for row r (no zero-init needed).
// Chunks touching row r: [qs>>6 .. ql>>6] (mod GPART), <= 7 wide;
// slots = chunk & 7, distinct. Whole window lives in ONE 64B line.
// ---------------------------------------------------------------------------
__global__ __launch_bounds__(256) void k_out2(const float2* __restrict__ partial,
                                              float* __restrict__ out) {
    const int r = blockIdx.x * 256 + threadIdx.x;
    const int j0 = r * KK;
    const int qs = j0 & (NPIX - 1);
    const int ql = (j0 + KK - 1) & (NPIX - 1);
    const int first = qs >> 6;
    const int last  = ql >> 6;
    const int cnt = ((last - first) & (GPART - 1)) + 1;
    const float2* p = partial + (size_t)r * NSLOT;
    float dot = 0.f, sum = 0.f;
    for (int i = 0; i < cnt; ++i) {
        float2 v = p[(first + i) & (NSLOT - 1)];
        dot += v.x; sum += v.y;
    }
    out[r] = dot / sum;
}

// ---------------------------------------------------------------------------
// Minimal fallback path (tiny ws): direct strided gathers.
// ---------------------------------------------------------------------------
__global__ __launch_bounds__(256) void k_s1(const float* __restrict__ ker,
                                            float* __restrict__ rcpS1) {
    int p = blockIdx.x * blockDim.x + threadIdx.x;
    const float* kp = ker + p;
    float a = 0.f;
    for (int s = 0; s < KK; ++s) a += kp[(size_t)s * NPIX];
    rcpS1[p] = 1.0f / a;
}

__global__ __launch_bounds__(256) void k_s2_fallback(const float* __restrict__ ker,
                                                     const float* __restrict__ rcpS1,
                                                     float* __restrict__ rcpS2) {
    int lane = threadIdx.x & 63;
    int q = blockIdx.x * 4 + (threadIdx.x >> 6);
    int base = q * KK;
    float acc = 0.f;
    for (int t = lane; t < KK; t += 64)
        acc += ker[base + t] * rcpS1[(base + t) & (NPIX - 1)];
    for (int m = 1; m < 64; m <<= 1) acc += __shfl_xor(acc, m);
    if (lane == 0) rcpS2[q] = 1.0f / acc;
}

__global__ __launch_bounds__(256) void k_out_fallback(const float* __restrict__ ker,
                                                      const float* __restrict__ rcpS1,
                                                      const float* __restrict__ rcpS2,
                                                      const float* __restrict__ in2,
                                                      float* __restrict__ out) {
    int lane = threadIdx.x & 63;
    int r = blockIdx.x * 4 + (threadIdx.x >> 6);
    float vsum = 0.f, vdot = 0.f;
    for (int u = lane; u < KK; u += 64) {
        int jj = r * KK + u;
        int t  = jj >> 16;
        int q  = jj & (NPIX - 1);
        int m  = q * KK + t;
        float v = ker[m] * rcpS1[m & (NPIX - 1)] * rcpS2[q];
        int y = q >> 8, x = q & 255;
        int a = t / LSZ, b = t - a * LSZ;
        float d = in2[refl(y + a) * HWD + refl(x + b)];
        vsum += v;
        vdot += d * v;
    }
    for (int mm = 1; mm < 64; mm <<= 1) {
        vsum += __shfl_xor(vsum, mm);
        vdot += __shfl_xor(vdot, mm);
    }
    if (lane == 0) out[r] = vdot / vsum;
}

extern "C" void kernel_launch(void* const* d_in, const int* in_sizes, int n_in,
                              void* d_out, int out_size, void* d_ws, size_t ws_size,
                              hipStream_t stream) {
    const float* inp = (const float*)d_in[0];   // (1,3,256,256)
    const float* ker = (const float*)d_in[1];   // (19,19,256,256)
    float* out = (float*)d_out;                 // (1,1,256,256)
    const float* in2 = inp + 2 * NPIX;          // channel 2

    float*  rcpS1   = (float*)d_ws;                           // NPIX
    float*  s1part  = rcpS1 + NPIX;                           // NS2*NPIX
    float2* partial = (float2*)(s1part + (size_t)NS2 * NPIX); // NPIX*NSLOT float2

    const size_t needed = ((size_t)NPIX * (1 + NS2) +
                           (size_t)NPIX * NSLOT * 2) * sizeof(float);  // ~8.25 MB

    if (ws_size >= needed) {
        dim3 g1(NPIX / 4 / 256, NS2);   // (64, 16)
        k_s1a<<<g1, 256, 0, stream>>>((const float4*)ker, (float4*)s1part);
        k_s1b<<<NPIX / 4 / 256, 256, 0, stream>>>((const float4*)s1part, (float4*)rcpS1);
        k_part<<<GPART, 384, 0, stream>>>(ker, rcpS1, in2, partial);
        k_out2<<<NPIX / 256, 256, 0, stream>>>(partial, out);
    } else {
        float* rcpS2 = rcpS1 + NPIX;   // fallback needs only 512 KB
        k_s1<<<NPIX / 256, 256, 0, stream>>>(ker, rcpS1);
        k_s2_fallback<<<NPIX / 4, 256, 0, stream>>>(ker, rcpS1, rcpS2);
        k_out_fallback<<<NPIX / 4, 256, 0, stream>>>(ker, rcpS1, rcpS2, in2, out);
    }
}